// Round 1
// baseline (1578.153 us; speedup 1.0000x reference)
//
#include <hip/hip_runtime.h>
#include <math.h>

#define B_   4
#define S_   1024
#define DIM_ 1024
#define H_   16
#define DH_  64
#define M_   (B_ * S_)   // 4096 rows

// ---------------------------------------------------------------------------
// Tiled fp32 GEMM: Y[m][n] = sum_d X[m][d] * W[n][d] + bias[n]
// 64x64 output tile per block, K-tile 16, 256 threads, 4x4 acc per thread.
// ---------------------------------------------------------------------------

__global__ __launch_bounds__(256) void qkv_gemm_kernel(
    const float* __restrict__ X,
    const float* __restrict__ Wq, const float* __restrict__ bq,
    const float* __restrict__ Wk, const float* __restrict__ bk,
    const float* __restrict__ Wv, const float* __restrict__ bv,
    float* __restrict__ Qo, float* __restrict__ Ko, float* __restrict__ Vo)
{
    const float* __restrict__ W;
    const float* __restrict__ bias;
    float* __restrict__ Y;
    if (blockIdx.z == 0)      { W = Wq; bias = bq; Y = Qo; }
    else if (blockIdx.z == 1) { W = Wk; bias = bk; Y = Ko; }
    else                      { W = Wv; bias = bv; Y = Vo; }

    __shared__ float As[16][64];
    __shared__ float Bs[16][64];

    const int tid  = threadIdx.x;
    const int tx   = tid & 15;        // n-group
    const int ty   = tid >> 4;        // m-group
    const int m0   = blockIdx.y * 64;
    const int n0   = blockIdx.x * 64;
    const int lrow = tid >> 2;        // 0..63
    const int lcol = (tid & 3) << 2;  // 0,4,8,12

    float acc[4][4] = {};

    for (int k0 = 0; k0 < DIM_; k0 += 16) {
        float4 a4 = *reinterpret_cast<const float4*>(X + (size_t)(m0 + lrow) * DIM_ + k0 + lcol);
        float4 b4 = *reinterpret_cast<const float4*>(W + (size_t)(n0 + lrow) * DIM_ + k0 + lcol);
        __syncthreads();
        As[lcol + 0][lrow] = a4.x; As[lcol + 1][lrow] = a4.y;
        As[lcol + 2][lrow] = a4.z; As[lcol + 3][lrow] = a4.w;
        Bs[lcol + 0][lrow] = b4.x; Bs[lcol + 1][lrow] = b4.y;
        Bs[lcol + 2][lrow] = b4.z; Bs[lcol + 3][lrow] = b4.w;
        __syncthreads();
        #pragma unroll
        for (int kk = 0; kk < 16; kk++) {
            float4 a = *reinterpret_cast<const float4*>(&As[kk][ty * 4]);
            float4 b = *reinterpret_cast<const float4*>(&Bs[kk][tx * 4]);
            float av[4] = {a.x, a.y, a.z, a.w};
            float bv2[4] = {b.x, b.y, b.z, b.w};
            #pragma unroll
            for (int i = 0; i < 4; i++)
                #pragma unroll
                for (int j = 0; j < 4; j++)
                    acc[i][j] = fmaf(av[i], bv2[j], acc[i][j]);
        }
    }

    // Epilogue: + bias, store into (B, H, S, DH) layout.
    const int nb = n0 + tx * 4;
    float4 bias4 = *reinterpret_cast<const float4*>(bias + nb);
    const int h = nb >> 6;     // head (tile never crosses a head boundary)
    const int d = nb & 63;
    #pragma unroll
    for (int i = 0; i < 4; i++) {
        const int m = m0 + ty * 4 + i;
        const int b = m >> 10;
        const int s = m & 1023;
        float4 r;
        r.x = acc[i][0] + bias4.x;
        r.y = acc[i][1] + bias4.y;
        r.z = acc[i][2] + bias4.z;
        r.w = acc[i][3] + bias4.w;
        *reinterpret_cast<float4*>(Y + (((size_t)(b * H_ + h) * S_ + s) * DH_) + d) = r;
    }
}

__global__ __launch_bounds__(256) void out_gemm_kernel(
    const float* __restrict__ X,      // (M, DIM) attention output
    const float* __restrict__ W,      // (DIM, DIM)
    const float* __restrict__ bias,   // (DIM,)
    float* __restrict__ Y)            // (M, DIM) row-major
{
    __shared__ float As[16][64];
    __shared__ float Bs[16][64];

    const int tid  = threadIdx.x;
    const int tx   = tid & 15;
    const int ty   = tid >> 4;
    const int m0   = blockIdx.y * 64;
    const int n0   = blockIdx.x * 64;
    const int lrow = tid >> 2;
    const int lcol = (tid & 3) << 2;

    float acc[4][4] = {};

    for (int k0 = 0; k0 < DIM_; k0 += 16) {
        float4 a4 = *reinterpret_cast<const float4*>(X + (size_t)(m0 + lrow) * DIM_ + k0 + lcol);
        float4 b4 = *reinterpret_cast<const float4*>(W + (size_t)(n0 + lrow) * DIM_ + k0 + lcol);
        __syncthreads();
        As[lcol + 0][lrow] = a4.x; As[lcol + 1][lrow] = a4.y;
        As[lcol + 2][lrow] = a4.z; As[lcol + 3][lrow] = a4.w;
        Bs[lcol + 0][lrow] = b4.x; Bs[lcol + 1][lrow] = b4.y;
        Bs[lcol + 2][lrow] = b4.z; Bs[lcol + 3][lrow] = b4.w;
        __syncthreads();
        #pragma unroll
        for (int kk = 0; kk < 16; kk++) {
            float4 a = *reinterpret_cast<const float4*>(&As[kk][ty * 4]);
            float4 b = *reinterpret_cast<const float4*>(&Bs[kk][tx * 4]);
            float av[4] = {a.x, a.y, a.z, a.w};
            float bv2[4] = {b.x, b.y, b.z, b.w};
            #pragma unroll
            for (int i = 0; i < 4; i++)
                #pragma unroll
                for (int j = 0; j < 4; j++)
                    acc[i][j] = fmaf(av[i], bv2[j], acc[i][j]);
        }
    }

    const int nb = n0 + tx * 4;
    float4 bias4 = *reinterpret_cast<const float4*>(bias + nb);
    #pragma unroll
    for (int i = 0; i < 4; i++) {
        const int m = m0 + ty * 4 + i;
        float4 r;
        r.x = acc[i][0] + bias4.x;
        r.y = acc[i][1] + bias4.y;
        r.z = acc[i][2] + bias4.z;
        r.w = acc[i][3] + bias4.w;
        *reinterpret_cast<float4*>(Y + (size_t)m * DIM_ + nb) = r;
    }
}

// ---------------------------------------------------------------------------
// RoPE (GPT-NeoX half-split), in-place on Q and K, layout (B, H, S, DH).
// out[j]    = x[j]*cos(a_j)    - x[j+32]*sin(a_j)
// out[j+32] = x[j+32]*cos(a_j) + x[j]*sin(a_j),  a_j = s * theta^(-j/32)
// ---------------------------------------------------------------------------
__global__ __launch_bounds__(256) void rope_kernel(float* __restrict__ Q,
                                                   float* __restrict__ K)
{
    const int idx = blockIdx.x * 256 + threadIdx.x;
    const int half = B_ * H_ * S_ * 32;   // 2,097,152 pairs each for Q and K
    float* p;
    int i;
    if (idx < half) { p = Q; i = idx; } else { p = K; i = idx - half; }
    const int j  = i & 31;
    const int s  = (i >> 5) & (S_ - 1);
    const int bh = i >> 15;
    float* row = p + ((size_t)bh * S_ + s) * DH_;
    const float freq = powf(10000.0f, -(float)j * (1.0f / 32.0f));
    const float ang = (float)s * freq;
    float sn, cs;
    sincosf(ang, &sn, &cs);
    const float x1 = row[j];
    const float x2 = row[j + 32];
    row[j]      = x1 * cs - x2 * sn;
    row[j + 32] = x2 * cs + x1 * sn;
}

// ---------------------------------------------------------------------------
// Attention: one thread per q-row, online softmax over all 1024 keys.
// K/V addresses are wave-uniform -> compiler emits scalar (s_load) reads;
// the FMA takes the K/V element as an SGPR operand. Q held in VGPRs.
// O written in (B, S, DIM) layout for the output projection.
// ---------------------------------------------------------------------------
__global__ __launch_bounds__(256) void attn_kernel(
    const float* __restrict__ Q, const float* __restrict__ K,
    const float* __restrict__ V, float* __restrict__ O)
{
    const int bh = blockIdx.x >> 2;                      // 0..63  (b*16+h)
    const int qr = ((blockIdx.x & 3) << 8) + threadIdx.x; // 0..1023

    const float* qp = Q + ((size_t)bh * S_ + qr) * DH_;
    float q[DH_];
    #pragma unroll
    for (int d = 0; d < DH_; d += 4) {
        float4 t = *reinterpret_cast<const float4*>(qp + d);
        q[d] = t.x; q[d + 1] = t.y; q[d + 2] = t.z; q[d + 3] = t.w;
    }

    const float* kb = K + (size_t)bh * S_ * DH_;
    const float* vb = V + (size_t)bh * S_ * DH_;

    float o[DH_];
    #pragma unroll
    for (int d = 0; d < DH_; d++) o[d] = 0.f;
    float mx = -3.0e38f;
    float l = 0.f;

    for (int kt = 0; kt < S_; kt += 16) {
        float sc[16];
        float tmax = mx;
        #pragma unroll
        for (int r = 0; r < 16; r++) {
            const float* kr = kb + (size_t)(kt + r) * DH_;   // wave-uniform
            float s = 0.f;
            #pragma unroll
            for (int d = 0; d < DH_; d++) s = fmaf(q[d], kr[d], s);
            s *= 0.125f;                                     // 1/sqrt(64)
            sc[r] = s;
            tmax = fmaxf(tmax, s);
        }
        const float alpha = __expf(mx - tmax);
        mx = tmax;
        l *= alpha;
        #pragma unroll
        for (int d = 0; d < DH_; d++) o[d] *= alpha;
        #pragma unroll
        for (int r = 0; r < 16; r++) {
            const float p = __expf(sc[r] - tmax);
            l += p;
            const float* vr = vb + (size_t)(kt + r) * DH_;   // wave-uniform
            #pragma unroll
            for (int d = 0; d < DH_; d++) o[d] = fmaf(p, vr[d], o[d]);
        }
    }

    const float inv = 1.0f / l;
    const int b = bh >> 4, h = bh & 15;
    float* op = O + ((size_t)(b * S_ + qr)) * DIM_ + h * DH_;
    #pragma unroll
    for (int d = 0; d < DH_; d += 4) {
        float4 t = make_float4(o[d] * inv, o[d + 1] * inv, o[d + 2] * inv, o[d + 3] * inv);
        *reinterpret_cast<float4*>(op + d) = t;
    }
}

// ---------------------------------------------------------------------------

extern "C" void kernel_launch(void* const* d_in, const int* in_sizes, int n_in,
                              void* d_out, int out_size, void* d_ws, size_t ws_size,
                              hipStream_t stream) {
    const float* x  = (const float*)d_in[0];
    const float* Wq = (const float*)d_in[1];
    const float* bq = (const float*)d_in[2];
    const float* Wk = (const float*)d_in[3];
    const float* bk = (const float*)d_in[4];
    const float* Wv = (const float*)d_in[5];
    const float* bv = (const float*)d_in[6];
    const float* Wo = (const float*)d_in[7];
    const float* bo = (const float*)d_in[8];
    float* out = (float*)d_out;

    const size_t n_elem = (size_t)B_ * S_ * DIM_;   // 4,194,304 floats = 16 MB
    float* Qb = (float*)d_ws;
    float* Kb = Qb + n_elem;
    float* Vb = Kb + n_elem;
    float* Ob = Vb + n_elem;

    // 1) QKV projections + bias, head-major output layout
    qkv_gemm_kernel<<<dim3(DIM_ / 64, M_ / 64, 3), 256, 0, stream>>>(
        x, Wq, bq, Wk, bk, Wv, bv, Qb, Kb, Vb);

    // 2) RoPE in-place on Q and K
    rope_kernel<<<dim3((2 * B_ * H_ * S_ * 32) / 256), 256, 0, stream>>>(Qb, Kb);

    // 3) Attention -> Ob (B, S, DIM)
    attn_kernel<<<dim3(B_ * H_ * 4), 256, 0, stream>>>(Qb, Kb, Vb, Ob);

    // 4) Output projection + bias -> d_out
    out_gemm_kernel<<<dim3(DIM_ / 64, M_ / 64, 1), 256, 0, stream>>>(Ob, Wo, bo, out);
}

// Round 2
// 639.975 us; speedup vs baseline: 2.4660x; 2.4660x over previous
//
#include <hip/hip_runtime.h>
#include <math.h>

#define B_   4
#define S_   1024
#define DIM_ 1024
#define H_   16
#define DH_  64
#define M_   (B_ * S_)   // 4096 rows

typedef __attribute__((ext_vector_type(8))) short bf16x8;
typedef __attribute__((ext_vector_type(4))) float f32x4;
#define MFMA16(a, b, c) __builtin_amdgcn_mfma_f32_16x16x32_bf16((a), (b), (c), 0, 0, 0)

__device__ __forceinline__ ushort f2bf(float f) {
    union { float f; unsigned u; } v; v.f = f;
    unsigned r = v.u + 0x7FFF + ((v.u >> 16) & 1);
    return (ushort)(r >> 16);
}

// ---------------------------------------------------------------------------
// QKV projection (fp32 math): Y[m][n] = sum_d X[m][d] * W[n][d] + b[n],
// fused RoPE on Q/K in the epilogue, bf16 outputs:
//   Q,K -> (B,H,S,DH) bf16 (RoPE applied)   V -> (B,H,DH,S) bf16 (transposed)
// RoPE pair (d, d+-32) lives in thread tid^8 (tx bit 3), same 64-lane wave.
// ---------------------------------------------------------------------------
__global__ __launch_bounds__(256) void qkv_gemm_kernel(
    const float* __restrict__ X,
    const float* __restrict__ Wq, const float* __restrict__ bq,
    const float* __restrict__ Wk, const float* __restrict__ bk,
    const float* __restrict__ Wv, const float* __restrict__ bv,
    ushort* __restrict__ Qo, ushort* __restrict__ Ko, ushort* __restrict__ VTo)
{
    const float* __restrict__ W;
    const float* __restrict__ bias;
    if (blockIdx.z == 0)      { W = Wq; bias = bq; }
    else if (blockIdx.z == 1) { W = Wk; bias = bk; }
    else                      { W = Wv; bias = bv; }

    __shared__ float As[16][64];
    __shared__ float Bs[16][64];

    const int tid  = threadIdx.x;
    const int tx   = tid & 15;        // n-group
    const int ty   = tid >> 4;        // m-group
    const int m0   = blockIdx.y * 64;
    const int n0   = blockIdx.x * 64;
    const int lrow = tid >> 2;        // 0..63
    const int lcol = (tid & 3) << 2;  // 0,4,8,12

    float acc[4][4] = {};

    for (int k0 = 0; k0 < DIM_; k0 += 16) {
        float4 a4 = *reinterpret_cast<const float4*>(X + (size_t)(m0 + lrow) * DIM_ + k0 + lcol);
        float4 b4 = *reinterpret_cast<const float4*>(W + (size_t)(n0 + lrow) * DIM_ + k0 + lcol);
        __syncthreads();
        As[lcol + 0][lrow] = a4.x; As[lcol + 1][lrow] = a4.y;
        As[lcol + 2][lrow] = a4.z; As[lcol + 3][lrow] = a4.w;
        Bs[lcol + 0][lrow] = b4.x; Bs[lcol + 1][lrow] = b4.y;
        Bs[lcol + 2][lrow] = b4.z; Bs[lcol + 3][lrow] = b4.w;
        __syncthreads();
        #pragma unroll
        for (int kk = 0; kk < 16; kk++) {
            float4 a = *reinterpret_cast<const float4*>(&As[kk][ty * 4]);
            float4 b = *reinterpret_cast<const float4*>(&Bs[kk][tx * 4]);
            float av[4] = {a.x, a.y, a.z, a.w};
            float bv2[4] = {b.x, b.y, b.z, b.w};
            #pragma unroll
            for (int i = 0; i < 4; i++)
                #pragma unroll
                for (int j = 0; j < 4; j++)
                    acc[i][j] = fmaf(av[i], bv2[j], acc[i][j]);
        }
    }

    const int nb = n0 + tx * 4;
    float4 bias4 = *reinterpret_cast<const float4*>(bias + nb);
    float bb[4] = {bias4.x, bias4.y, bias4.z, bias4.w};
    const int h = nb >> 6;     // head (64-tile never crosses head boundary)
    const int d = nb & 63;

    if (blockIdx.z < 2) {
        // RoPE + bf16 store, (B,H,S,DH)
        ushort* Y = (blockIdx.z == 0) ? Qo : Ko;
        const int jj = d & 31;
        #pragma unroll
        for (int i = 0; i < 4; i++) {
            const int m = m0 + ty * 4 + i;
            const int b = m >> 10;
            const int s = m & 1023;
            float r[4], p[4];
            #pragma unroll
            for (int j = 0; j < 4; j++) r[j] = acc[i][j] + bb[j];
            #pragma unroll
            for (int j = 0; j < 4; j++) p[j] = __shfl_xor(r[j], 8, 64);
            ushort4 pack;
            ushort* pk = (ushort*)&pack;
            #pragma unroll
            for (int j = 0; j < 4; j++) {
                float freq = powf(10000.0f, -(float)(jj + j) * (1.0f / 32.0f));
                float ang = (float)s * freq;
                float sn, cs;
                sincosf(ang, &sn, &cs);
                float val = (d < 32) ? (r[j] * cs - p[j] * sn)
                                     : (r[j] * cs + p[j] * sn);
                pk[j] = f2bf(val);
            }
            *reinterpret_cast<ushort4*>(Y + ((size_t)(b * H_ + h) * S_ + s) * DH_ + d) = pack;
        }
    } else {
        // V transposed bf16 store, (B,H,DH,S)
        const int m = m0 + ty * 4;
        const int b = m >> 10;
        const int s0 = m & 1023;
        const size_t base = (size_t)(b * H_ + h) * DH_;
        #pragma unroll
        for (int j = 0; j < 4; j++) {
            ushort4 pack;
            pack.x = f2bf(acc[0][j] + bb[j]);
            pack.y = f2bf(acc[1][j] + bb[j]);
            pack.z = f2bf(acc[2][j] + bb[j]);
            pack.w = f2bf(acc[3][j] + bb[j]);
            *reinterpret_cast<ushort4*>(VTo + (base + d + j) * S_ + s0) = pack;
        }
    }
}

// ---------------------------------------------------------------------------
// Output projection (fp32), row-major store + bias.
// ---------------------------------------------------------------------------
__global__ __launch_bounds__(256) void out_gemm_kernel(
    const float* __restrict__ X, const float* __restrict__ W,
    const float* __restrict__ bias, float* __restrict__ Y)
{
    __shared__ float As[16][64];
    __shared__ float Bs[16][64];

    const int tid  = threadIdx.x;
    const int tx   = tid & 15;
    const int ty   = tid >> 4;
    const int m0   = blockIdx.y * 64;
    const int n0   = blockIdx.x * 64;
    const int lrow = tid >> 2;
    const int lcol = (tid & 3) << 2;

    float acc[4][4] = {};

    for (int k0 = 0; k0 < DIM_; k0 += 16) {
        float4 a4 = *reinterpret_cast<const float4*>(X + (size_t)(m0 + lrow) * DIM_ + k0 + lcol);
        float4 b4 = *reinterpret_cast<const float4*>(W + (size_t)(n0 + lrow) * DIM_ + k0 + lcol);
        __syncthreads();
        As[lcol + 0][lrow] = a4.x; As[lcol + 1][lrow] = a4.y;
        As[lcol + 2][lrow] = a4.z; As[lcol + 3][lrow] = a4.w;
        Bs[lcol + 0][lrow] = b4.x; Bs[lcol + 1][lrow] = b4.y;
        Bs[lcol + 2][lrow] = b4.z; Bs[lcol + 3][lrow] = b4.w;
        __syncthreads();
        #pragma unroll
        for (int kk = 0; kk < 16; kk++) {
            float4 a = *reinterpret_cast<const float4*>(&As[kk][ty * 4]);
            float4 b = *reinterpret_cast<const float4*>(&Bs[kk][tx * 4]);
            float av[4] = {a.x, a.y, a.z, a.w};
            float bv2[4] = {b.x, b.y, b.z, b.w};
            #pragma unroll
            for (int i = 0; i < 4; i++)
                #pragma unroll
                for (int j = 0; j < 4; j++)
                    acc[i][j] = fmaf(av[i], bv2[j], acc[i][j]);
        }
    }

    const int nb = n0 + tx * 4;
    float4 bias4 = *reinterpret_cast<const float4*>(bias + nb);
    #pragma unroll
    for (int i = 0; i < 4; i++) {
        const int m = m0 + ty * 4 + i;
        float4 r;
        r.x = acc[i][0] + bias4.x;
        r.y = acc[i][1] + bias4.y;
        r.z = acc[i][2] + bias4.z;
        r.w = acc[i][3] + bias4.w;
        *reinterpret_cast<float4*>(Y + (size_t)m * DIM_ + nb) = r;
    }
}

// ---------------------------------------------------------------------------
// Flash attention, bf16 MFMA (16x16x32).
// Block = 4 waves, one (b,h) x 64-q-row tile. Wave owns 16 q-rows.
// K-tiles of 64 keys. P goes C-layout -> LDS -> A-layout (m120 pattern).
// LDS rows padded to 72 bf16 -> ds_read_b128 is 2-way on banks (free).
// ---------------------------------------------------------------------------
#define LDP 72

__global__ __launch_bounds__(256) void attn_mfma_kernel(
    const ushort* __restrict__ Qh, const ushort* __restrict__ Kh,
    const ushort* __restrict__ VT, float* __restrict__ O)
{
    const int bh = blockIdx.x >> 4;           // 0..63
    const int q0 = (blockIdx.x & 15) * 64;

    __shared__ ushort Qs[64 * LDP];
    __shared__ ushort Ks[64 * LDP];
    __shared__ ushort Vs[64 * LDP];           // [dh][key]
    __shared__ ushort Ps[4][16 * LDP];        // per-wave P

    const int tid  = threadIdx.x;
    const int wave = tid >> 6;
    const int lane = tid & 63;
    const int l15  = lane & 15;
    const int quad = lane >> 4;

    // stage Q tile (64x64 bf16): thread -> row tid>>2, 16 elems
    {
        const ushort* src = Qh + ((size_t)bh * S_ + q0) * DH_;
        const int r = tid >> 2, c = (tid & 3) * 16;
        *reinterpret_cast<int4*>(Qs + r * LDP + c)     = *reinterpret_cast<const int4*>(src + r * 64 + c);
        *reinterpret_cast<int4*>(Qs + r * LDP + c + 8) = *reinterpret_cast<const int4*>(src + r * 64 + c + 8);
    }

    f32x4 o_acc[4];
    #pragma unroll
    for (int c = 0; c < 4; c++) o_acc[c] = (f32x4){0.f, 0.f, 0.f, 0.f};
    float m_r[4] = {-3.0e38f, -3.0e38f, -3.0e38f, -3.0e38f};
    float l_r[4] = {0.f, 0.f, 0.f, 0.f};

    for (int kt = 0; kt < S_; kt += 64) {
        __syncthreads();
        // stage K tile
        {
            const ushort* src = Kh + ((size_t)bh * S_ + kt) * DH_;
            const int r = tid >> 2, c = (tid & 3) * 16;
            *reinterpret_cast<int4*>(Ks + r * LDP + c)     = *reinterpret_cast<const int4*>(src + r * 64 + c);
            *reinterpret_cast<int4*>(Ks + r * LDP + c + 8) = *reinterpret_cast<const int4*>(src + r * 64 + c + 8);
        }
        // stage V^T tile: rows d, cols kt..kt+63
        {
            const ushort* src = VT + (size_t)bh * DH_ * S_ + kt;
            const int r = tid >> 2, c = (tid & 3) * 16;
            *reinterpret_cast<int4*>(Vs + r * LDP + c)     = *reinterpret_cast<const int4*>(src + (size_t)r * S_ + c);
            *reinterpret_cast<int4*>(Vs + r * LDP + c + 8) = *reinterpret_cast<const int4*>(src + (size_t)r * S_ + c + 8);
        }
        __syncthreads();

        // S = Q K^T  (wave's 16 q-rows x 64 keys)
        bf16x8 aq0 = *reinterpret_cast<const bf16x8*>(Qs + (wave * 16 + l15) * LDP + quad * 8);
        bf16x8 aq1 = *reinterpret_cast<const bf16x8*>(Qs + (wave * 16 + l15) * LDP + 32 + quad * 8);

        f32x4 sc[4];
        #pragma unroll
        for (int c = 0; c < 4; c++) {
            const ushort* kr = Ks + (c * 16 + l15) * LDP;
            bf16x8 b0 = *reinterpret_cast<const bf16x8*>(kr + quad * 8);
            bf16x8 b1 = *reinterpret_cast<const bf16x8*>(kr + 32 + quad * 8);
            f32x4 s = (f32x4){0.f, 0.f, 0.f, 0.f};
            s = MFMA16(aq0, b0, s);
            s = MFMA16(aq1, b1, s);
            sc[c] = s;
        }
        #pragma unroll
        for (int c = 0; c < 4; c++)
            #pragma unroll
            for (int r = 0; r < 4; r++) sc[c][r] *= 0.125f;   // 1/sqrt(64)

        // online softmax; C-layout row = quad*4 + r, col = c*16 + l15
        float tm[4], alpha[4], rs[4];
        #pragma unroll
        for (int r = 0; r < 4; r++) {
            tm[r] = fmaxf(fmaxf(sc[0][r], sc[1][r]), fmaxf(sc[2][r], sc[3][r]));
            #pragma unroll
            for (int s = 1; s < 16; s <<= 1) tm[r] = fmaxf(tm[r], __shfl_xor(tm[r], s, 64));
            float mn = fmaxf(m_r[r], tm[r]);
            alpha[r] = __expf(m_r[r] - mn);
            m_r[r] = mn;
            rs[r] = 0.f;
        }
        ushort* pw = &Ps[wave][0];
        #pragma unroll
        for (int c = 0; c < 4; c++)
            #pragma unroll
            for (int r = 0; r < 4; r++) {
                float p = __expf(sc[c][r] - m_r[r]);
                rs[r] += p;
                pw[(quad * 4 + r) * LDP + c * 16 + l15] = f2bf(p);
            }
        #pragma unroll
        for (int r = 0; r < 4; r++) {
            #pragma unroll
            for (int s = 1; s < 16; s <<= 1) rs[r] += __shfl_xor(rs[r], s, 64);
            l_r[r] = l_r[r] * alpha[r] + rs[r];
        }
        #pragma unroll
        for (int c = 0; c < 4; c++)
            #pragma unroll
            for (int r = 0; r < 4; r++) o_acc[c][r] *= alpha[r];

        // O += P V   (P re-read in A-layout from wave-private LDS)
        bf16x8 pa0 = *reinterpret_cast<const bf16x8*>(pw + l15 * LDP + quad * 8);
        bf16x8 pa1 = *reinterpret_cast<const bf16x8*>(pw + l15 * LDP + 32 + quad * 8);
        #pragma unroll
        for (int c = 0; c < 4; c++) {
            const ushort* vr = Vs + (c * 16 + l15) * LDP;
            bf16x8 b0 = *reinterpret_cast<const bf16x8*>(vr + quad * 8);
            bf16x8 b1 = *reinterpret_cast<const bf16x8*>(vr + 32 + quad * 8);
            o_acc[c] = MFMA16(pa0, b0, o_acc[c]);
            o_acc[c] = MFMA16(pa1, b1, o_acc[c]);
        }
    }

    // epilogue: /l, write O (B,S,DIM) fp32
    const int b = bh >> 4, h = bh & 15;
    #pragma unroll
    for (int r = 0; r < 4; r++) {
        const float inv = 1.0f / l_r[r];
        const int qrow = q0 + wave * 16 + quad * 4 + r;
        float* dst = O + ((size_t)(b * S_ + qrow)) * DIM_ + h * 64 + l15;
        dst[0]  = o_acc[0][r] * inv;
        dst[16] = o_acc[1][r] * inv;
        dst[32] = o_acc[2][r] * inv;
        dst[48] = o_acc[3][r] * inv;
    }
}

// ---------------------------------------------------------------------------

extern "C" void kernel_launch(void* const* d_in, const int* in_sizes, int n_in,
                              void* d_out, int out_size, void* d_ws, size_t ws_size,
                              hipStream_t stream) {
    const float* x  = (const float*)d_in[0];
    const float* Wq = (const float*)d_in[1];
    const float* bq = (const float*)d_in[2];
    const float* Wk = (const float*)d_in[3];
    const float* bk = (const float*)d_in[4];
    const float* Wv = (const float*)d_in[5];
    const float* bv = (const float*)d_in[6];
    const float* Wo = (const float*)d_in[7];
    const float* bo = (const float*)d_in[8];
    float* out = (float*)d_out;

    const size_t n_elem = (size_t)B_ * S_ * DIM_;   // 4,194,304
    ushort* Qh = (ushort*)d_ws;                     // bf16 (B,H,S,DH)   8 MB
    ushort* Kh = Qh + n_elem;                       // bf16 (B,H,S,DH)   8 MB
    ushort* VT = Kh + n_elem;                       // bf16 (B,H,DH,S)   8 MB
    float*  Ob = (float*)(VT + n_elem);             // fp32 (B,S,DIM)   16 MB

    // 1) QKV projections + bias + fused RoPE -> bf16 Q,K head-major; bf16 V^T
    qkv_gemm_kernel<<<dim3(DIM_ / 64, M_ / 64, 3), 256, 0, stream>>>(
        x, Wq, bq, Wk, bk, Wv, bv, Qh, Kh, VT);

    // 2) MFMA flash attention -> Ob (B,S,DIM) fp32
    attn_mfma_kernel<<<dim3(B_ * H_ * (S_ / 64)), 256, 0, stream>>>(Qh, Kh, VT, Ob);

    // 3) Output projection + bias -> d_out
    out_gemm_kernel<<<dim3(DIM_ / 64, M_ / 64, 1), 256, 0, stream>>>(Ob, Wo, bo, out);
}

// Round 3
// 227.548 us; speedup vs baseline: 6.9355x; 2.8125x over previous
//
#include <hip/hip_runtime.h>
#include <math.h>

#define B_   4
#define S_   1024
#define DIM_ 1024
#define H_   16
#define DH_  64
#define M_   (B_ * S_)   // 4096 rows
#define K_   1024

typedef __attribute__((ext_vector_type(8))) short bf16x8;
typedef __attribute__((ext_vector_type(4))) float f32x4;
#define MFMA16(a, b, c) __builtin_amdgcn_mfma_f32_16x16x32_bf16((a), (b), (c), 0, 0, 0)

__device__ __forceinline__ ushort f2bf(float f) {
    union { float f; unsigned u; } v; v.f = f;
    unsigned r = v.u + 0x7FFF + ((v.u >> 16) & 1);
    return (ushort)(r >> 16);
}

__device__ __forceinline__ void gload16(const void* g, void* lds) {
    __builtin_amdgcn_global_load_lds(
        (const __attribute__((address_space(1))) unsigned int*)g,
        (__attribute__((address_space(3))) unsigned int*)lds, 16, 0, 0);
}

// ---------------------------------------------------------------------------
// fp32 -> bf16 convert: x (1048576 f4) then Wq,Wk,Wv -> Wb concat, Wo -> Wob.
// ---------------------------------------------------------------------------
__global__ __launch_bounds__(256) void conv_kernel(
    const float* __restrict__ x,  const float* __restrict__ Wq,
    const float* __restrict__ Wk, const float* __restrict__ Wv,
    const float* __restrict__ Wo,
    ushort* __restrict__ Xb, ushort* __restrict__ Wb, ushort* __restrict__ Wob)
{
    const int idx = blockIdx.x * 256 + threadIdx.x;   // 0 .. 2097151
    const float4* src;
    ushort* dst;
    if (idx < 1048576) {
        src = reinterpret_cast<const float4*>(x) + idx;
        dst = Xb + (size_t)idx * 4;
    } else {
        const int w = idx - 1048576;
        const int which = w >> 18;        // 0..3
        const int off = w & 262143;
        const float* s = (which == 0) ? Wq : (which == 1) ? Wk : (which == 2) ? Wv : Wo;
        src = reinterpret_cast<const float4*>(s) + off;
        dst = (which < 3) ? (Wb + (size_t)which * 1048576 + (size_t)off * 4)
                          : (Wob + (size_t)off * 4);
    }
    float4 v = *src;
    ushort4 o;
    o.x = f2bf(v.x); o.y = f2bf(v.y); o.z = f2bf(v.z); o.w = f2bf(v.w);
    *reinterpret_cast<ushort4*>(dst) = o;
}

// RoPE tables: cosT/sinT[s*32 + j] = cos/sin(s * 10000^(-j/32))
__global__ __launch_bounds__(256) void rope_table_kernel(float* __restrict__ cosT,
                                                         float* __restrict__ sinT)
{
    const int idx = blockIdx.x * 256 + threadIdx.x;   // 0..32767
    const int s = idx >> 5, j = idx & 31;
    const float freq = powf(10000.0f, -(float)j * (1.0f / 32.0f));
    float sn, cs;
    sincosf((float)s * freq, &sn, &cs);
    cosT[idx] = cs;
    sinT[idx] = sn;
}

// ---------------------------------------------------------------------------
// QKV bf16 MFMA GEMM (m97 structure): C[m][n] = sum_k Xb[m][k] Wb[n][k],
// 128x128 tile, BK=32, 4 waves, global_load_lds(16B). N = 3072 (Q|K|V zones).
// Epilogue: +bias, RoPE (table) for Q/K -> (B,H,S,DH) bf16; V -> (B,H,DH,S).
// ---------------------------------------------------------------------------
__global__ __launch_bounds__(256) void qkv_mfma_kernel(
    const ushort* __restrict__ Xb, const ushort* __restrict__ Wb,
    const float* __restrict__ bq, const float* __restrict__ bk,
    const float* __restrict__ bv,
    const float* __restrict__ cosT, const float* __restrict__ sinT,
    ushort* __restrict__ Qh, ushort* __restrict__ Kh, ushort* __restrict__ VT)
{
    __shared__ ushort As[128 * 32];
    __shared__ ushort Bs[128 * 32];

    const int tid  = threadIdx.x;
    const int wave = tid >> 6;
    const int lane = tid & 63;
    const int l15  = lane & 15;
    const int quad = lane >> 4;
    const int wr   = wave & 1;        // m half
    const int wc   = wave >> 1;       // n half
    const int m0   = blockIdx.y * 128;
    const int n0   = blockIdx.x * 128;
    const int lrow = lane >> 2;       // 0..15
    const int lcol = (lane & 3) * 8;  // bf16 elems

    const ushort* Ag = Xb + (size_t)m0 * K_;
    const ushort* Bg = Wb + (size_t)n0 * K_;

    f32x4 acc[4][4];
    #pragma unroll
    for (int i = 0; i < 4; i++)
        #pragma unroll
        for (int j = 0; j < 4; j++) acc[i][j] = (f32x4){0.f, 0.f, 0.f, 0.f};

    for (int k0 = 0; k0 < K_; k0 += 32) {
        __syncthreads();
        #pragma unroll
        for (int j = 0; j < 2; j++) {
            const int rb = (j * 4 + wave) * 16;
            gload16(Ag + (size_t)(rb + lrow) * K_ + k0 + lcol, As + rb * 32);
            gload16(Bg + (size_t)(rb + lrow) * K_ + k0 + lcol, Bs + rb * 32);
        }
        __syncthreads();

        bf16x8 af[4], bf[4];
        #pragma unroll
        for (int i = 0; i < 4; i++)
            af[i] = *reinterpret_cast<const bf16x8*>(As + (wr * 64 + i * 16 + l15) * 32 + quad * 8);
        #pragma unroll
        for (int i = 0; i < 4; i++)
            bf[i] = *reinterpret_cast<const bf16x8*>(Bs + (wc * 64 + i * 16 + l15) * 32 + quad * 8);
        #pragma unroll
        for (int i = 0; i < 4; i++)
            #pragma unroll
            for (int j = 0; j < 4; j++)
                acc[i][j] = MFMA16(af[i], bf[j], acc[i][j]);
    }

    // ---- epilogue ----
    const int zone = n0 >> 10;            // 0=Q 1=K 2=V
    const int nl0  = n0 & 1023;
    const int n_base = nl0 + wc * 64 + l15;   // + ni*16
    const int h = (nl0 + wc * 64) >> 6;       // lane-uniform head
    const int r_m0 = m0 + wr * 64 + quad * 4; // + mi*16 + r

    if (zone < 2) {
        ushort* Y = zone ? Kh : Qh;
        const float* bias = zone ? bk : bq;
        float bias_l[4];
        #pragma unroll
        for (int ni = 0; ni < 4; ni++) bias_l[ni] = bias[n_base + ni * 16];
        #pragma unroll
        for (int mi = 0; mi < 4; mi++)
            #pragma unroll
            for (int r = 0; r < 4; r++) {
                const int m = r_m0 + mi * 16 + r;
                const int b = m >> 10, s = m & 1023;
                const float cs0 = cosT[s * 32 + l15],      sn0 = sinT[s * 32 + l15];
                const float cs1 = cosT[s * 32 + 16 + l15], sn1 = sinT[s * 32 + 16 + l15];
                ushort* row = Y + ((size_t)(b * H_ + h) * S_ + s) * DH_;
                #pragma unroll
                for (int ni = 0; ni < 4; ni++) {
                    const float c = acc[mi][ni][r] + bias_l[ni];
                    const float p = acc[mi][ni ^ 2][r] + bias_l[ni ^ 2];
                    const float cs = (ni & 1) ? cs1 : cs0;
                    const float sn = (ni & 1) ? sn1 : sn0;
                    const float val = (ni & 2) ? fmaf(p, sn, c * cs) : fmaf(-p, sn, c * cs);
                    row[ni * 16 + l15] = f2bf(val);
                }
            }
    } else {
        float bias_l[4];
        #pragma unroll
        for (int ni = 0; ni < 4; ni++) bias_l[ni] = bv[n_base + ni * 16];
        #pragma unroll
        for (int mi = 0; mi < 4; mi++)
            #pragma unroll
            for (int r = 0; r < 4; r++) {
                const int m = r_m0 + mi * 16 + r;
                const int b = m >> 10, s = m & 1023;
                const size_t base = (size_t)(b * H_ + h) * DH_;
                #pragma unroll
                for (int ni = 0; ni < 4; ni++) {
                    const int d = ni * 16 + l15;
                    VT[(base + d) * S_ + s] = f2bf(acc[mi][ni][r] + bias_l[ni]);
                }
            }
    }
}

// ---------------------------------------------------------------------------
// Output projection bf16 MFMA: out[m][n] = sum_k Ob[m][k] Wob[n][k] + bo[n].
// ---------------------------------------------------------------------------
__global__ __launch_bounds__(256) void out_mfma_kernel(
    const ushort* __restrict__ Ob, const ushort* __restrict__ Wob,
    const float* __restrict__ bo, float* __restrict__ out)
{
    __shared__ ushort As[128 * 32];
    __shared__ ushort Bs[128 * 32];

    const int tid  = threadIdx.x;
    const int wave = tid >> 6;
    const int lane = tid & 63;
    const int l15  = lane & 15;
    const int quad = lane >> 4;
    const int wr   = wave & 1;
    const int wc   = wave >> 1;
    const int m0   = blockIdx.y * 128;
    const int n0   = blockIdx.x * 128;
    const int lrow = lane >> 2;
    const int lcol = (lane & 3) * 8;

    const ushort* Ag = Ob + (size_t)m0 * K_;
    const ushort* Bg = Wob + (size_t)n0 * K_;

    f32x4 acc[4][4];
    #pragma unroll
    for (int i = 0; i < 4; i++)
        #pragma unroll
        for (int j = 0; j < 4; j++) acc[i][j] = (f32x4){0.f, 0.f, 0.f, 0.f};

    for (int k0 = 0; k0 < K_; k0 += 32) {
        __syncthreads();
        #pragma unroll
        for (int j = 0; j < 2; j++) {
            const int rb = (j * 4 + wave) * 16;
            gload16(Ag + (size_t)(rb + lrow) * K_ + k0 + lcol, As + rb * 32);
            gload16(Bg + (size_t)(rb + lrow) * K_ + k0 + lcol, Bs + rb * 32);
        }
        __syncthreads();

        bf16x8 af[4], bf[4];
        #pragma unroll
        for (int i = 0; i < 4; i++)
            af[i] = *reinterpret_cast<const bf16x8*>(As + (wr * 64 + i * 16 + l15) * 32 + quad * 8);
        #pragma unroll
        for (int i = 0; i < 4; i++)
            bf[i] = *reinterpret_cast<const bf16x8*>(Bs + (wc * 64 + i * 16 + l15) * 32 + quad * 8);
        #pragma unroll
        for (int i = 0; i < 4; i++)
            #pragma unroll
            for (int j = 0; j < 4; j++)
                acc[i][j] = MFMA16(af[i], bf[j], acc[i][j]);
    }

    const int n_base = n0 + wc * 64 + l15;
    float bias_l[4];
    #pragma unroll
    for (int ni = 0; ni < 4; ni++) bias_l[ni] = bo[n_base + ni * 16];
    const int r_m0 = m0 + wr * 64 + quad * 4;
    #pragma unroll
    for (int mi = 0; mi < 4; mi++)
        #pragma unroll
        for (int r = 0; r < 4; r++) {
            const int m = r_m0 + mi * 16 + r;
            float* row = out + (size_t)m * DIM_;
            #pragma unroll
            for (int ni = 0; ni < 4; ni++)
                row[n_base + ni * 16] = acc[mi][ni][r] + bias_l[ni];
        }
}

// ---------------------------------------------------------------------------
// Flash attention, bf16 MFMA (16x16x32). Unchanged from R1 except bf16 O out.
// ---------------------------------------------------------------------------
#define LDP 72

__global__ __launch_bounds__(256) void attn_mfma_kernel(
    const ushort* __restrict__ Qh, const ushort* __restrict__ Kh,
    const ushort* __restrict__ VT, ushort* __restrict__ O)
{
    const int bh = blockIdx.x >> 4;           // 0..63
    const int q0 = (blockIdx.x & 15) * 64;

    __shared__ ushort Qs[64 * LDP];
    __shared__ ushort Ks[64 * LDP];
    __shared__ ushort Vs[64 * LDP];           // [dh][key]
    __shared__ ushort Ps[4][16 * LDP];        // per-wave P

    const int tid  = threadIdx.x;
    const int wave = tid >> 6;
    const int lane = tid & 63;
    const int l15  = lane & 15;
    const int quad = lane >> 4;

    {
        const ushort* src = Qh + ((size_t)bh * S_ + q0) * DH_;
        const int r = tid >> 2, c = (tid & 3) * 16;
        *reinterpret_cast<int4*>(Qs + r * LDP + c)     = *reinterpret_cast<const int4*>(src + r * 64 + c);
        *reinterpret_cast<int4*>(Qs + r * LDP + c + 8) = *reinterpret_cast<const int4*>(src + r * 64 + c + 8);
    }

    f32x4 o_acc[4];
    #pragma unroll
    for (int c = 0; c < 4; c++) o_acc[c] = (f32x4){0.f, 0.f, 0.f, 0.f};
    float m_r[4] = {-3.0e38f, -3.0e38f, -3.0e38f, -3.0e38f};
    float l_r[4] = {0.f, 0.f, 0.f, 0.f};

    for (int kt = 0; kt < S_; kt += 64) {
        __syncthreads();
        {
            const ushort* src = Kh + ((size_t)bh * S_ + kt) * DH_;
            const int r = tid >> 2, c = (tid & 3) * 16;
            *reinterpret_cast<int4*>(Ks + r * LDP + c)     = *reinterpret_cast<const int4*>(src + r * 64 + c);
            *reinterpret_cast<int4*>(Ks + r * LDP + c + 8) = *reinterpret_cast<const int4*>(src + r * 64 + c + 8);
        }
        {
            const ushort* src = VT + (size_t)bh * DH_ * S_ + kt;
            const int r = tid >> 2, c = (tid & 3) * 16;
            *reinterpret_cast<int4*>(Vs + r * LDP + c)     = *reinterpret_cast<const int4*>(src + (size_t)r * S_ + c);
            *reinterpret_cast<int4*>(Vs + r * LDP + c + 8) = *reinterpret_cast<const int4*>(src + (size_t)r * S_ + c + 8);
        }
        __syncthreads();

        bf16x8 aq0 = *reinterpret_cast<const bf16x8*>(Qs + (wave * 16 + l15) * LDP + quad * 8);
        bf16x8 aq1 = *reinterpret_cast<const bf16x8*>(Qs + (wave * 16 + l15) * LDP + 32 + quad * 8);

        f32x4 sc[4];
        #pragma unroll
        for (int c = 0; c < 4; c++) {
            const ushort* kr = Ks + (c * 16 + l15) * LDP;
            bf16x8 b0 = *reinterpret_cast<const bf16x8*>(kr + quad * 8);
            bf16x8 b1 = *reinterpret_cast<const bf16x8*>(kr + 32 + quad * 8);
            f32x4 s = (f32x4){0.f, 0.f, 0.f, 0.f};
            s = MFMA16(aq0, b0, s);
            s = MFMA16(aq1, b1, s);
            sc[c] = s;
        }
        #pragma unroll
        for (int c = 0; c < 4; c++)
            #pragma unroll
            for (int r = 0; r < 4; r++) sc[c][r] *= 0.125f;

        float tm[4], alpha[4], rs[4];
        #pragma unroll
        for (int r = 0; r < 4; r++) {
            tm[r] = fmaxf(fmaxf(sc[0][r], sc[1][r]), fmaxf(sc[2][r], sc[3][r]));
            #pragma unroll
            for (int s = 1; s < 16; s <<= 1) tm[r] = fmaxf(tm[r], __shfl_xor(tm[r], s, 64));
            float mn = fmaxf(m_r[r], tm[r]);
            alpha[r] = __expf(m_r[r] - mn);
            m_r[r] = mn;
            rs[r] = 0.f;
        }
        ushort* pw = &Ps[wave][0];
        #pragma unroll
        for (int c = 0; c < 4; c++)
            #pragma unroll
            for (int r = 0; r < 4; r++) {
                float p = __expf(sc[c][r] - m_r[r]);
                rs[r] += p;
                pw[(quad * 4 + r) * LDP + c * 16 + l15] = f2bf(p);
            }
        #pragma unroll
        for (int r = 0; r < 4; r++) {
            #pragma unroll
            for (int s = 1; s < 16; s <<= 1) rs[r] += __shfl_xor(rs[r], s, 64);
            l_r[r] = l_r[r] * alpha[r] + rs[r];
        }
        #pragma unroll
        for (int c = 0; c < 4; c++)
            #pragma unroll
            for (int r = 0; r < 4; r++) o_acc[c][r] *= alpha[r];

        bf16x8 pa0 = *reinterpret_cast<const bf16x8*>(pw + l15 * LDP + quad * 8);
        bf16x8 pa1 = *reinterpret_cast<const bf16x8*>(pw + l15 * LDP + 32 + quad * 8);
        #pragma unroll
        for (int c = 0; c < 4; c++) {
            const ushort* vr = Vs + (c * 16 + l15) * LDP;
            bf16x8 b0 = *reinterpret_cast<const bf16x8*>(vr + quad * 8);
            bf16x8 b1 = *reinterpret_cast<const bf16x8*>(vr + 32 + quad * 8);
            o_acc[c] = MFMA16(pa0, b0, o_acc[c]);
            o_acc[c] = MFMA16(pa1, b1, o_acc[c]);
        }
    }

    const int b = bh >> 4, h = bh & 15;
    #pragma unroll
    for (int r = 0; r < 4; r++) {
        const float inv = 1.0f / l_r[r];
        const int qrow = q0 + wave * 16 + quad * 4 + r;
        ushort* dst = O + ((size_t)(b * S_ + qrow)) * DIM_ + h * 64 + l15;
        dst[0]  = f2bf(o_acc[0][r] * inv);
        dst[16] = f2bf(o_acc[1][r] * inv);
        dst[32] = f2bf(o_acc[2][r] * inv);
        dst[48] = f2bf(o_acc[3][r] * inv);
    }
}

// ---------------------------------------------------------------------------

extern "C" void kernel_launch(void* const* d_in, const int* in_sizes, int n_in,
                              void* d_out, int out_size, void* d_ws, size_t ws_size,
                              hipStream_t stream) {
    const float* x  = (const float*)d_in[0];
    const float* Wq = (const float*)d_in[1];
    const float* bq = (const float*)d_in[2];
    const float* Wk = (const float*)d_in[3];
    const float* bk = (const float*)d_in[4];
    const float* Wv = (const float*)d_in[5];
    const float* bv = (const float*)d_in[6];
    const float* Wo = (const float*)d_in[7];
    const float* bo = (const float*)d_in[8];
    float* out = (float*)d_out;

    const size_t n_elem = (size_t)B_ * S_ * DIM_;   // 4,194,304
    ushort* Xb  = (ushort*)d_ws;                    // 8 MB  (M,K) bf16
    ushort* Wb  = Xb + n_elem;                      // 6 MB  (3072,K) bf16
    ushort* Wob = Wb + 3 * 1048576;                 // 2 MB  (1024,K) bf16
    ushort* Qh  = Wob + 1048576;                    // 8 MB  (B,H,S,DH)
    ushort* Kh  = Qh + n_elem;                      // 8 MB
    ushort* VT  = Kh + n_elem;                      // 8 MB  (B,H,DH,S)
    ushort* Ob  = VT + n_elem;                      // 8 MB  (B,S,DIM) bf16
    float* cosT = (float*)(Ob + n_elem);            // 128 KB
    float* sinT = cosT + S_ * 32;                   // 128 KB

    conv_kernel<<<dim3(8192), 256, 0, stream>>>(x, Wq, Wk, Wv, Wo, Xb, Wb, Wob);
    rope_table_kernel<<<dim3(128), 256, 0, stream>>>(cosT, sinT);

    qkv_mfma_kernel<<<dim3(3072 / 128, M_ / 128), 256, 0, stream>>>(
        Xb, Wb, bq, bk, bv, cosT, sinT, Qh, Kh, VT);

    attn_mfma_kernel<<<dim3(B_ * H_ * (S_ / 64)), 256, 0, stream>>>(Qh, Kh, VT, Ob);

    out_mfma_kernel<<<dim3(DIM_ / 128, M_ / 128), 256, 0, stream>>>(Ob, Wob, bo, out);
}